// Round 1
// baseline (881.142 us; speedup 1.0000x reference)
//
#include <hip/hip_runtime.h>

#define NB 8
#define CI 128
#define CO 256
#define KS 7
#define LL 16384
#define CK (CI * KS)   // 896
#define LT 64

// ---------- transpose x (NB, CI, LL) -> xT (NB, LL, CI) ----------
__global__ __launch_bounds__(256) void transpose_x(const float* __restrict__ x,
                                                   float* __restrict__ xT) {
    __shared__ float tile[32][33];
    const int n  = blockIdx.z;
    const int c0 = blockIdx.y * 32;
    const int l0 = blockIdx.x * 32;
    const int tx = threadIdx.x;   // 0..31
    const int ty = threadIdx.y;   // 0..7
    const float* xs = x + (size_t)n * CI * LL;
    float* xd = xT + (size_t)n * LL * CI;
    #pragma unroll
    for (int i = ty; i < 32; i += 8)
        tile[i][tx] = xs[(size_t)(c0 + i) * LL + (l0 + tx)];
    __syncthreads();
    #pragma unroll
    for (int i = ty; i < 32; i += 8)
        xd[(size_t)(l0 + i) * CI + (c0 + tx)] = tile[tx][i];
}

// ---------- transpose w (CO, CI, KS) -> wT (KS, CI, CO) ----------
__global__ __launch_bounds__(256) void transpose_w(const float* __restrict__ w,
                                                   float* __restrict__ wT) {
    const int t = blockIdx.x * 256 + threadIdx.x;
    if (t >= KS * CI * CO) return;
    const int o = t & (CO - 1);
    const int c = (t >> 8) & (CI - 1);
    const int k = t / (CO * CI);
    wT[t] = w[(size_t)o * CK + c * KS + k];
}

// ---------- main GEMM: out[n,o,l] = sum_{c,k} col * w + bias ----------
// block: one n, LT=64 l-values, all 256 o. 256 threads, each 4o x 16l regs.
template <bool XPOSED>
__global__ __launch_bounds__(256) void iconv_gemm(
    const float* __restrict__ x,    // (NB, CI, LL) original
    const float* __restrict__ xT,   // (NB, LL, CI) transposed
    const int*   __restrict__ idx,  // (KS, LL), -1 = masked
    const float* __restrict__ w,    // (CO, CI, KS) original
    const float* __restrict__ wT,   // (KS, CI, CO) transposed
    const float* __restrict__ bias, // (CO)
    float* __restrict__ out)        // (NB, CO, LL)
{
    __shared__ float col[CI][LT];   // 32 KB

    const int n  = blockIdx.y;
    const int l0 = blockIdx.x * LT;
    const int t  = threadIdx.x;
    const int ot = t & 63;          // wave-uniform lt = t>>6 -> broadcast LDS reads
    const int lt = t >> 6;
    const int j    = t >> 2;        // staging: l within tile
    const int part = t & 3;         // staging: c quarter

    float acc[4][16];
    #pragma unroll
    for (int oo = 0; oo < 4; ++oo) {
        const float bv = bias[ot * 4 + oo];
        #pragma unroll
        for (int ll = 0; ll < 16; ++ll) acc[oo][ll] = bv;
    }

    for (int k = 0; k < KS; ++k) {
        __syncthreads();
        const int i = idx[k * LL + l0 + j];
        if (XPOSED) {
            if (i >= 0) {
                const float4* row =
                    reinterpret_cast<const float4*>(xT + ((size_t)n * LL + i) * CI);
                #pragma unroll
                for (int q = 0; q < 8; ++q) {
                    const float4 v = row[part * 8 + q];
                    const int c = (part * 8 + q) * 4;
                    col[c + 0][j] = v.x;
                    col[c + 1][j] = v.y;
                    col[c + 2][j] = v.z;
                    col[c + 3][j] = v.w;
                }
            } else {
                #pragma unroll
                for (int q = 0; q < 8; ++q) {
                    const int c = (part * 8 + q) * 4;
                    col[c + 0][j] = 0.f;
                    col[c + 1][j] = 0.f;
                    col[c + 2][j] = 0.f;
                    col[c + 3][j] = 0.f;
                }
            }
        } else {
            const float* xr = x + (size_t)n * CI * LL;
            for (int q = 0; q < 32; ++q) {
                const int c = part * 32 + q;
                col[c][j] = (i >= 0) ? xr[(size_t)c * LL + i] : 0.f;
            }
        }
        __syncthreads();

        #pragma unroll 2
        for (int c = 0; c < CI; ++c) {
            float4 b4[4];
            const float4* colv = reinterpret_cast<const float4*>(&col[c][lt * 16]);
            b4[0] = colv[0]; b4[1] = colv[1]; b4[2] = colv[2]; b4[3] = colv[3];
            const float* bv = reinterpret_cast<const float*>(b4);
            float wv[4];
            if (XPOSED) {
                const float4 w4 = *reinterpret_cast<const float4*>(
                    wT + ((size_t)k * CI + c) * CO + ot * 4);
                wv[0] = w4.x; wv[1] = w4.y; wv[2] = w4.z; wv[3] = w4.w;
            } else {
                #pragma unroll
                for (int oo = 0; oo < 4; ++oo)
                    wv[oo] = w[(size_t)(ot * 4 + oo) * CK + c * KS + k];
            }
            #pragma unroll
            for (int oo = 0; oo < 4; ++oo)
                #pragma unroll
                for (int ll = 0; ll < 16; ++ll)
                    acc[oo][ll] += wv[oo] * bv[ll];
        }
    }

    #pragma unroll
    for (int oo = 0; oo < 4; ++oo) {
        float* orow = out + ((size_t)n * CO + (ot * 4 + oo)) * LL + l0 + lt * 16;
        float4* o4 = reinterpret_cast<float4*>(orow);
        #pragma unroll
        for (int q = 0; q < 4; ++q)
            o4[q] = make_float4(acc[oo][q * 4 + 0], acc[oo][q * 4 + 1],
                                acc[oo][q * 4 + 2], acc[oo][q * 4 + 3]);
    }
}

extern "C" void kernel_launch(void* const* d_in, const int* in_sizes, int n_in,
                              void* d_out, int out_size, void* d_ws, size_t ws_size,
                              hipStream_t stream) {
    const float* x    = (const float*)d_in[0];
    const int*   idx  = (const int*)d_in[1];
    const float* w    = (const float*)d_in[2];
    const float* bias = (const float*)d_in[3];
    float* out = (float*)d_out;

    const size_t xt_bytes = (size_t)NB * LL * CI * sizeof(float);   // 64 MiB
    const size_t wt_bytes = (size_t)KS * CI * CO * sizeof(float);   // ~0.9 MiB

    if (ws_size >= xt_bytes + wt_bytes) {
        float* xT = (float*)d_ws;
        float* wT = (float*)((char*)d_ws + xt_bytes);
        transpose_x<<<dim3(LL / 32, CI / 32, NB), dim3(32, 8), 0, stream>>>(x, xT);
        transpose_w<<<dim3((KS * CI * CO + 255) / 256), 256, 0, stream>>>(w, wT);
        iconv_gemm<true><<<dim3(LL / LT, NB), 256, 0, stream>>>(
            x, xT, idx, w, wT, bias, out);
    } else {
        // workspace too small: direct-gather fallback (slower, still correct)
        iconv_gemm<false><<<dim3(LL / LT, NB), 256, 0, stream>>>(
            x, nullptr, idx, w, nullptr, bias, out);
    }
}

// Round 2
// 263.570 us; speedup vs baseline: 3.3431x; 3.3431x over previous
//
#include <hip/hip_runtime.h>
#include <stdint.h>

#define NB 8
#define CI 128
#define CO 256
#define KS 7
#define LL 16384
#define CK (CI * KS)   // 896

typedef _Float16 half8 __attribute__((ext_vector_type(8)));
typedef _Float16 half2v __attribute__((ext_vector_type(2)));
typedef float floatx4 __attribute__((ext_vector_type(4)));

__device__ __forceinline__ void load16_to_lds(const void* g, void* l) {
    __builtin_amdgcn_global_load_lds(
        (const __attribute__((address_space(1))) void*)g,
        (__attribute__((address_space(3))) void*)l, 16, 0, 0);
}

// ---------- x (NB, CI, LL) f32 -> xT (NB, LL, CI) f16 ----------
__global__ __launch_bounds__(256) void convert_x(const float* __restrict__ x,
                                                 _Float16* __restrict__ xT) {
    __shared__ float tile[32][129];   // [c][l]
    const int n  = blockIdx.z;
    const int c0 = blockIdx.y * 32;
    const int l0 = blockIdx.x * 128;
    const int t  = threadIdx.x;
    const float* xs = x + (size_t)n * CI * LL + (size_t)c0 * LL + l0;
    {
        const int lj = t & 127, ci = t >> 7;   // 2 c-rows per iter
        #pragma unroll
        for (int it = 0; it < 16; ++it)
            tile[ci + it * 2][lj] = xs[(size_t)(ci + it * 2) * LL + lj];
    }
    __syncthreads();
    _Float16* xd = xT + (size_t)n * LL * CI + (size_t)l0 * CI + c0;
    const int cp = t & 15, lr = t >> 4;        // 16 l-rows per iter
    #pragma unroll
    for (int it = 0; it < 8; ++it) {
        const int l = lr + it * 16;
        half2v v;
        v[0] = (_Float16)tile[cp * 2][l];
        v[1] = (_Float16)tile[cp * 2 + 1][l];
        *(half2v*)(xd + (size_t)l * CI + cp * 2) = v;
    }
}

// ---------- w (CO, CI, KS) f32 -> wT (CO, KS*CI) f16, ck-order k*128+c ----------
__global__ __launch_bounds__(256) void convert_w(const float* __restrict__ w,
                                                 _Float16* __restrict__ wT) {
    const int t = blockIdx.x * 256 + threadIdx.x;
    if (t >= CO * CK) return;
    const int o = t / CK;
    const int r = t - o * CK;
    const int k = r >> 7;
    const int c = r & 127;
    wT[t] = (_Float16)w[(size_t)o * CK + c * KS + k];
}

__global__ void zero_fill(float* __restrict__ z) {
    z[threadIdx.x] = 0.f;   // 64 threads -> 256 B
}

// ---------- MFMA GEMM: out[n,o,l] = sum_{k,c} xT[n, idx[k,l], c] * wT[o, k*128+c] + bias[o]
// block: 128 o x 128 l tile, 256 threads (4 waves, 2x2 wave grid of 64x64),
// K-loop: 7 k-slices x 4 c-chunks of 32, m97-style 2-barrier global_load_lds staging.
__global__ __launch_bounds__(256) void iconv_mfma(
    const _Float16* __restrict__ xT,   // (NB, LL, CI)
    const int*      __restrict__ idx,  // (KS, LL), -1 = masked
    const _Float16* __restrict__ wT,   // (CO, CK)
    const float*    __restrict__ bias, // (CO)
    const _Float16* __restrict__ zrow, // 256 B zeros
    float*          __restrict__ out)  // (NB, CO, LL)
{
    __shared__ _Float16 a_lds[128 * 32];   // [o][ck] 8 KB
    __shared__ _Float16 b_lds[128 * 32];   // [l][ck] 8 KB

    const int l0 = blockIdx.x * 128;
    const int o0 = blockIdx.y * 128;
    const int n  = blockIdx.z;
    const int t  = threadIdx.x;
    const int lane = t & 63;
    const int wv = t >> 6;
    const int wo = (wv >> 1) * 64;
    const int wl = (wv & 1) * 64;
    const int m16 = lane & 15;
    const int q8  = (lane >> 4) * 8;

    floatx4 acc[4][4];
    #pragma unroll
    for (int i = 0; i < 4; ++i)
        #pragma unroll
        for (int j = 0; j < 4; ++j) acc[i][j] = (floatx4)0.f;

    // staging: chunk = r*256 + t -> row = chunk>>2 (o or l in tile), part = chunk&3
    const int row  = t >> 2;
    const int part = t & 3;
    const _Float16* wbase0 = wT + (size_t)(o0 + row) * CK + part * 8;
    const _Float16* wbase1 = wT + (size_t)(o0 + 64 + row) * CK + part * 8;
    const _Float16* xbase  = xT + (size_t)n * LL * CI;
    const _Float16* zbase  = zrow + part * 8;

    for (int k = 0; k < KS; ++k) {
        const int i0 = idx[k * LL + l0 + row];
        const int i1 = idx[k * LL + l0 + 64 + row];
        const _Float16* s0 = (i0 >= 0) ? xbase + (size_t)i0 * CI + part * 8 : zbase;
        const _Float16* s1 = (i1 >= 0) ? xbase + (size_t)i1 * CI + part * 8 : zbase;
        const _Float16* w0 = wbase0 + k * CI;
        const _Float16* w1 = wbase1 + k * CI;
        for (int c0 = 0; c0 < CI; c0 += 32) {
            __syncthreads();
            load16_to_lds(s0 + c0, b_lds + t * 8);
            load16_to_lds(s1 + c0, b_lds + (256 + t) * 8);
            load16_to_lds(w0 + c0, a_lds + t * 8);
            load16_to_lds(w1 + c0, a_lds + (256 + t) * 8);
            __syncthreads();

            half8 af[4], bf[4];
            #pragma unroll
            for (int mf = 0; mf < 4; ++mf)
                af[mf] = *(const half8*)(a_lds + (wo + mf * 16 + m16) * 32 + q8);
            #pragma unroll
            for (int nf = 0; nf < 4; ++nf)
                bf[nf] = *(const half8*)(b_lds + (wl + nf * 16 + m16) * 32 + q8);
            #pragma unroll
            for (int mf = 0; mf < 4; ++mf)
                #pragma unroll
                for (int nf = 0; nf < 4; ++nf)
                    acc[mf][nf] = __builtin_amdgcn_mfma_f32_16x16x32_f16(
                        af[mf], bf[nf], acc[mf][nf], 0, 0, 0);
        }
    }

    // epilogue: D[m][n]: m(row)=o=(lane>>4)*4+reg, n(col)=l=lane&15
    const int r4 = (lane >> 4) * 4;
    #pragma unroll
    for (int mf = 0; mf < 4; ++mf) {
        const int obase = o0 + wo + mf * 16 + r4;
        const floatx4 b4 = *(const floatx4*)(bias + obase);
        #pragma unroll
        for (int nf = 0; nf < 4; ++nf) {
            const int l = l0 + wl + nf * 16 + m16;
            float* op = out + ((size_t)n * CO + obase) * LL + l;
            #pragma unroll
            for (int r = 0; r < 4; ++r)
                op[(size_t)r * LL] = acc[mf][nf][r] + b4[r];
        }
    }
}

// ---------- fp32 fallback (only if workspace too small) ----------
__global__ __launch_bounds__(256) void iconv_fallback(
    const float* __restrict__ x, const int* __restrict__ idx,
    const float* __restrict__ w, const float* __restrict__ bias,
    float* __restrict__ out)
{
    __shared__ float col[CI][64];
    const int n  = blockIdx.y;
    const int l0 = blockIdx.x * 64;
    const int t  = threadIdx.x;
    const int ot = t & 63, lt = t >> 6;
    const int j = t >> 2, part = t & 3;
    float acc[4][16];
    #pragma unroll
    for (int oo = 0; oo < 4; ++oo) {
        const float bv = bias[ot * 4 + oo];
        #pragma unroll
        for (int ll = 0; ll < 16; ++ll) acc[oo][ll] = bv;
    }
    for (int k = 0; k < KS; ++k) {
        __syncthreads();
        const int i = idx[k * LL + l0 + j];
        const float* xr = x + (size_t)n * CI * LL;
        for (int q = 0; q < 32; ++q) {
            const int c = part * 32 + q;
            col[c][j] = (i >= 0) ? xr[(size_t)c * LL + i] : 0.f;
        }
        __syncthreads();
        for (int c = 0; c < CI; ++c) {
            const float* bv = &col[c][lt * 16];
            float wv[4];
            #pragma unroll
            for (int oo = 0; oo < 4; ++oo)
                wv[oo] = w[(size_t)(ot * 4 + oo) * CK + c * KS + k];
            #pragma unroll
            for (int oo = 0; oo < 4; ++oo)
                #pragma unroll
                for (int ll = 0; ll < 16; ++ll)
                    acc[oo][ll] += wv[oo] * bv[ll];
        }
    }
    #pragma unroll
    for (int oo = 0; oo < 4; ++oo) {
        float* orow = out + ((size_t)n * CO + (ot * 4 + oo)) * LL + l0 + lt * 16;
        #pragma unroll
        for (int q = 0; q < 16; ++q) orow[q] = acc[oo][q];
    }
}

extern "C" void kernel_launch(void* const* d_in, const int* in_sizes, int n_in,
                              void* d_out, int out_size, void* d_ws, size_t ws_size,
                              hipStream_t stream) {
    const float* x    = (const float*)d_in[0];
    const int*   idx  = (const int*)d_in[1];
    const float* w    = (const float*)d_in[2];
    const float* bias = (const float*)d_in[3];
    float* out = (float*)d_out;

    const size_t xt_bytes = (size_t)NB * LL * CI * sizeof(_Float16);  // 32 MiB
    const size_t wt_bytes = (size_t)CO * CK * sizeof(_Float16);       // 448 KiB
    const size_t need = xt_bytes + wt_bytes + 256;

    if (ws_size >= need) {
        _Float16* xT = (_Float16*)d_ws;
        _Float16* wT = (_Float16*)((char*)d_ws + xt_bytes);
        float*    zr = (float*)((char*)d_ws + xt_bytes + wt_bytes);
        convert_x<<<dim3(LL / 128, CI / 32, NB), 256, 0, stream>>>(x, xT);
        convert_w<<<dim3((CO * CK + 255) / 256), 256, 0, stream>>>(w, wT);
        zero_fill<<<1, 64, 0, stream>>>(zr);
        iconv_mfma<<<dim3(LL / 128, CO / 128, NB), 256, 0, stream>>>(
            xT, idx, wT, bias, (const _Float16*)zr, out);
    } else {
        iconv_fallback<<<dim3(LL / 64, NB), 256, 0, stream>>>(x, idx, w, bias, out);
    }
}

// Round 3
// 261.765 us; speedup vs baseline: 3.3662x; 1.0069x over previous
//
#include <hip/hip_runtime.h>
#include <stdint.h>

#define NB 8
#define CI 128
#define CO 256
#define KS 7
#define LL 16384
#define CK (CI * KS)   // 896

typedef _Float16 half8 __attribute__((ext_vector_type(8)));
typedef _Float16 half2v __attribute__((ext_vector_type(2)));
typedef float floatx4 __attribute__((ext_vector_type(4)));
typedef uint32_t uintx4 __attribute__((ext_vector_type(4)));

__device__ __forceinline__ void load16_to_lds(const void* g, void* l) {
    __builtin_amdgcn_global_load_lds(
        (const __attribute__((address_space(1))) void*)g,
        (__attribute__((address_space(3))) void*)l, 16, 0, 0);
}

// ---------- x (NB, CI, LL) f32 -> xT (NB, LL, CI) f16 ----------
// 64 l x 128 c tile. Read: float4 along l (coalesced). Pack c-pairs to u32.
// LDS tile[l][cp] pad+1 (2-way alias only). Write: dwordx4, wave-contiguous 1KB.
__global__ __launch_bounds__(256) void convert_x(const float* __restrict__ x,
                                                 _Float16* __restrict__ xT) {
    __shared__ uint32_t tile[64][65];   // 16.6 KB
    const int n  = blockIdx.y;
    const int l0 = blockIdx.x * 64;
    const int t  = threadIdx.x;
    const float* xs = x + (size_t)n * CI * LL + l0;

    const int l4  = (t & 15) * 4;
    const int cpr = t >> 4;            // 0..15
    #pragma unroll
    for (int p = 0; p < 4; ++p) {
        const int cp = cpr + p * 16;   // c-pair 0..63
        const float4 a4 = *(const float4*)(xs + (size_t)(2 * cp) * LL + l4);
        const float4 b4 = *(const float4*)(xs + (size_t)(2 * cp + 1) * LL + l4);
        half2v h;
        h[0] = (_Float16)a4.x; h[1] = (_Float16)b4.x;
        tile[l4 + 0][cp] = __builtin_bit_cast(uint32_t, h);
        h[0] = (_Float16)a4.y; h[1] = (_Float16)b4.y;
        tile[l4 + 1][cp] = __builtin_bit_cast(uint32_t, h);
        h[0] = (_Float16)a4.z; h[1] = (_Float16)b4.z;
        tile[l4 + 2][cp] = __builtin_bit_cast(uint32_t, h);
        h[0] = (_Float16)a4.w; h[1] = (_Float16)b4.w;
        tile[l4 + 3][cp] = __builtin_bit_cast(uint32_t, h);
    }
    __syncthreads();

    const int lw  = t >> 4;            // 0..15
    const int cp0 = (t & 15) * 4;
    _Float16* xd = xT + (size_t)n * LL * CI + (size_t)l0 * CI;
    #pragma unroll
    for (int p = 0; p < 4; ++p) {
        const int l = lw + p * 16;
        uintx4 d;
        d[0] = tile[l][cp0 + 0];
        d[1] = tile[l][cp0 + 1];
        d[2] = tile[l][cp0 + 2];
        d[3] = tile[l][cp0 + 3];
        *(uintx4*)(xd + (size_t)l * CI + cp0 * 2) = d;
    }
}

// ---------- w (CO, CI, KS) f32 -> wT (CO, KS*CI) f16 ck-order, + 128-half zero row ----------
__global__ __launch_bounds__(256) void convert_w(const float* __restrict__ w,
                                                 _Float16* __restrict__ wT) {
    const int t = blockIdx.x * 256 + threadIdx.x;
    if (t >= CO * CK + 128) return;
    if (t >= CO * CK) { wT[t] = (_Float16)0.f; return; }
    const int o = t / CK;
    const int r = t - o * CK;
    const int k = r >> 7;
    const int c = r & 127;
    wT[t] = (_Float16)w[(size_t)o * CK + c * KS + k];
}

// ---------- MFMA GEMM, BK=64, 14 sync-pairs, idx prefetched to regs ----------
__global__ __launch_bounds__(256) void iconv_mfma(
    const _Float16* __restrict__ xT,   // (NB, LL, CI)
    const int*      __restrict__ idx,  // (KS, LL), -1 = masked
    const _Float16* __restrict__ wT,   // (CO, CK)
    const float*    __restrict__ bias, // (CO)
    const _Float16* __restrict__ zrow, // 128 halfs of zeros
    float*          __restrict__ out)  // (NB, CO, LL)
{
    __shared__ _Float16 a_lds[128 * 64];   // 16 KB
    __shared__ _Float16 b_lds[128 * 64];   // 16 KB

    const int l0 = blockIdx.x * 128;
    const int o0 = blockIdx.y * 128;
    const int n  = blockIdx.z;
    const int t  = threadIdx.x;
    const int lane = t & 63;
    const int wv = t >> 6;
    const int wo = (wv >> 1) * 64;
    const int wl = (wv & 1) * 64;
    const int m16 = lane & 15;
    const int q8  = (lane >> 4) * 8;

    floatx4 acc[4][4];
    #pragma unroll
    for (int i = 0; i < 4; ++i)
        #pragma unroll
        for (int j = 0; j < 4; ++j) acc[i][j] = (floatx4)0.f;

    // staging: 128 rows x 128 B per operand; u = i*256+t -> row=u>>3, part=u&7
    const int srow = t >> 3;   // 0..31
    const int part = t & 7;    // 0..7

    // prefetch all idx into regs: no dependent loads between barriers
    int iv[KS][4];
    #pragma unroll
    for (int k = 0; k < KS; ++k)
        #pragma unroll
        for (int i = 0; i < 4; ++i)
            iv[k][i] = idx[k * LL + l0 + i * 32 + srow];

    const _Float16* xbase = xT + (size_t)n * LL * CI;
    const _Float16* wbase = wT + (size_t)(o0 + srow) * CK + part * 8;
    const int dst = srow * 64 + part * 8;   // halfs; + i*2048

    for (int k = 0; k < KS; ++k) {
        for (int c0 = 0; c0 < CI; c0 += 64) {
            __syncthreads();
            #pragma unroll
            for (int i = 0; i < 4; ++i) {
                const int ii = iv[k][i];
                const _Float16* bs = (ii >= 0)
                    ? (xbase + (size_t)ii * CI + c0 + part * 8)
                    : (zrow + c0 + part * 8);
                load16_to_lds(bs, b_lds + i * 2048 + dst);
                load16_to_lds(wbase + (size_t)i * 32 * CK + k * CI + c0,
                              a_lds + i * 2048 + dst);
            }
            __syncthreads();

            #pragma unroll
            for (int kk = 0; kk < 2; ++kk) {
                half8 af[4], bf[4];
                #pragma unroll
                for (int mf = 0; mf < 4; ++mf)
                    af[mf] = *(const half8*)(a_lds + (wo + mf * 16 + m16) * 64 + kk * 32 + q8);
                #pragma unroll
                for (int nf = 0; nf < 4; ++nf)
                    bf[nf] = *(const half8*)(b_lds + (wl + nf * 16 + m16) * 64 + kk * 32 + q8);
                #pragma unroll
                for (int mf = 0; mf < 4; ++mf)
                    #pragma unroll
                    for (int nf = 0; nf < 4; ++nf)
                        acc[mf][nf] = __builtin_amdgcn_mfma_f32_16x16x32_f16(
                            af[mf], bf[nf], acc[mf][nf], 0, 0, 0);
            }
        }
    }

    // epilogue: D[m][n]: m(row)=o=(lane>>4)*4+reg, n(col)=l=lane&15
    const int r4 = (lane >> 4) * 4;
    #pragma unroll
    for (int mf = 0; mf < 4; ++mf) {
        const int obase = o0 + wo + mf * 16 + r4;
        const floatx4 b4 = *(const floatx4*)(bias + obase);
        #pragma unroll
        for (int nf = 0; nf < 4; ++nf) {
            const int l = l0 + wl + nf * 16 + m16;
            float* op = out + ((size_t)n * CO + obase) * LL + l;
            #pragma unroll
            for (int r = 0; r < 4; ++r)
                op[(size_t)r * LL] = acc[mf][nf][r] + b4[r];
        }
    }
}

// ---------- fp32 fallback (only if workspace too small) ----------
__global__ __launch_bounds__(256) void iconv_fallback(
    const float* __restrict__ x, const int* __restrict__ idx,
    const float* __restrict__ w, const float* __restrict__ bias,
    float* __restrict__ out)
{
    __shared__ float col[CI][64];
    const int n  = blockIdx.y;
    const int l0 = blockIdx.x * 64;
    const int t  = threadIdx.x;
    const int ot = t & 63, lt = t >> 6;
    const int j = t >> 2, part = t & 3;
    float acc[4][16];
    #pragma unroll
    for (int oo = 0; oo < 4; ++oo) {
        const float bv = bias[ot * 4 + oo];
        #pragma unroll
        for (int ll = 0; ll < 16; ++ll) acc[oo][ll] = bv;
    }
    for (int k = 0; k < KS; ++k) {
        __syncthreads();
        const int i = idx[k * LL + l0 + j];
        const float* xr = x + (size_t)n * CI * LL;
        for (int q = 0; q < 32; ++q) {
            const int c = part * 32 + q;
            col[c][j] = (i >= 0) ? xr[(size_t)c * LL + i] : 0.f;
        }
        __syncthreads();
        for (int c = 0; c < CI; ++c) {
            const float* bv = &col[c][lt * 16];
            float wv[4];
            #pragma unroll
            for (int oo = 0; oo < 4; ++oo)
                wv[oo] = w[(size_t)(ot * 4 + oo) * CK + c * KS + k];
            #pragma unroll
            for (int oo = 0; oo < 4; ++oo)
                #pragma unroll
                for (int ll = 0; ll < 16; ++ll)
                    acc[oo][ll] += wv[oo] * bv[ll];
        }
    }
    #pragma unroll
    for (int oo = 0; oo < 4; ++oo) {
        float* orow = out + ((size_t)n * CO + (ot * 4 + oo)) * LL + l0 + lt * 16;
        #pragma unroll
        for (int q = 0; q < 16; ++q) orow[q] = acc[oo][q];
    }
}

extern "C" void kernel_launch(void* const* d_in, const int* in_sizes, int n_in,
                              void* d_out, int out_size, void* d_ws, size_t ws_size,
                              hipStream_t stream) {
    const float* x    = (const float*)d_in[0];
    const int*   idx  = (const int*)d_in[1];
    const float* w    = (const float*)d_in[2];
    const float* bias = (const float*)d_in[3];
    float* out = (float*)d_out;

    const size_t xt_bytes = (size_t)NB * LL * CI * sizeof(_Float16);     // 32 MiB
    const size_t wt_elems = (size_t)CO * CK + 128;                       // incl. zero row
    const size_t need = xt_bytes + wt_elems * sizeof(_Float16);

    if (ws_size >= need) {
        _Float16* xT = (_Float16*)d_ws;
        _Float16* wT = (_Float16*)((char*)d_ws + xt_bytes);
        const _Float16* zr = wT + (size_t)CO * CK;
        convert_x<<<dim3(LL / 64, NB), 256, 0, stream>>>(x, xT);
        convert_w<<<dim3(((int)wt_elems + 255) / 256), 256, 0, stream>>>(w, wT);
        iconv_mfma<<<dim3(LL / 128, CO / 128, NB), 256, 0, stream>>>(
            xT, idx, wT, bias, zr, out);
    } else {
        iconv_fallback<<<dim3(LL / 64, NB), 256, 0, stream>>>(x, idx, w, bias, out);
    }
}